// Round 16
// baseline (226.382 us; speedup 1.0000x reference)
//
#include <hip/hip_runtime.h>
#include <math.h>

#define B_ 2
#define L_ 2048
#define D_ 512
#define H_ 16
#define HD_ 32
#define FF_ 2048
#define BL_ 4096
#define EPS_ 1e-5f

typedef unsigned short ushort;
typedef unsigned int uint;
typedef __attribute__((ext_vector_type(8))) short bf16x8;
typedef __attribute__((ext_vector_type(4))) float f32x4;
typedef __attribute__((ext_vector_type(4))) uint u32x4;

__device__ __forceinline__ ushort bf16r(float f) {
  uint u = __float_as_uint(f);
  uint r = (u + 0x7FFFu + ((u >> 16) & 1u)) >> 16;
  return (ushort)r;
}
__device__ __forceinline__ float bf2f(uint u) { return __uint_as_float(u << 16); }

__device__ __forceinline__ float wsum(float v) {
#pragma unroll
  for (int o = 32; o; o >>= 1) v += __shfl_xor(v, o);
  return v;
}

// fast tanh-form GELU
__device__ __forceinline__ float gelu_fast(float x) {
  float t = x + 0.044715f * x * x * x;
  float e = exp2f(fminf(2.302118131f * t, 80.f));
  return x * e / (1.f + e);
}

__device__ __forceinline__ void gload16(const void* g, void* l) {
  __builtin_amdgcn_global_load_lds(
      (const __attribute__((address_space(1))) void*)g,
      (__attribute__((address_space(3))) void*)l, 16, 0, 0);
}

// ================================================================ bf16 MFMA GEMM
// C[m,n] = epi( sum_k A[m,k] * W[n,k] );  SPK=1: split-K x2 over z.
// tile classes (256 thr): (64,128) 4 waves x 64x32; (64,64) 4 waves x 32x32;
//                         (32,64) 4 waves x 16x32 (max TLP for small GEMMs)
template <int TMv, int TNv, int EPI, int BROW, int GELU, int RES, int OUTF, int OUTB, int SPK>
__global__ __launch_bounds__(256, 2) void gemm_bf_k(
    const ushort* __restrict__ A, const ushort* __restrict__ W,
    const float* __restrict__ bias, const float* __restrict__ res,
    float* __restrict__ Cf, ushort* __restrict__ Cb,
    const int M, const int N, const int Kd, const long sW, const long sC,
    const int ldC,
    const float* __restrict__ tab, ushort* __restrict__ Qb,
    ushort* __restrict__ Kb, ushort* __restrict__ Vb) {
  constexpr int MF = (TMv == 64) ? ((TNv == 128) ? 4 : 2) : ((TMv == 128) ? 4 : 1);
  constexpr int NF = (TNv == 128) ? ((TMv == 128) ? 4 : 2) : 2;
  __shared__ __align__(16) ushort As[TMv * 64];
  __shared__ __align__(16) ushort Ws[TNv * 64];
  const int tid = threadIdx.x;
  const int wid = tid >> 6, lane = tid & 63;
  const int lane15 = lane & 15, lgrp = lane >> 4;
  const int rowoff = (TMv == 128) ? (wid >> 1) * 64
                   : (TMv == 64 ? ((TNv == 64) ? (wid >> 1) * 32 : 0)
                                : (wid >> 1) * 16);
  const int wnoff = (TMv == 128) ? (wid & 1) * 64
                                 : ((TNv == 128) ? wid * 32 : (wid & 1) * 32);
  const int bm = blockIdx.y * TMv, bn = blockIdx.x * TNv;
  const int z = blockIdx.z;
  const int lda = SPK ? (Kd << 1) : Kd;
  const int kh = SPK ? (z & 1) : 0;
  const int zb = SPK ? (z >> 1) : z;
  const ushort* Az = A + (size_t)kh * Kd;
  const ushort* Wz = W + (size_t)zb * sW + (size_t)kh * Kd;

  f32x4 acc[MF][NF];
#pragma unroll
  for (int i = 0; i < MF; ++i)
#pragma unroll
    for (int j = 0; j < NF; ++j) acc[i][j] = (f32x4){0.f, 0.f, 0.f, 0.f};

  for (int k0 = 0; k0 < Kd; k0 += 64) {
    __syncthreads();
#pragma unroll
    for (int i = 0; i < (TMv * 8) / 256; ++i) {
      const int cb = i * 256 + wid * 64;
      const int chunk = cb + lane;
      const int ml = chunk >> 3;
      const int c16 = (chunk & 7) ^ (ml & 7);
      gload16(Az + (size_t)(bm + ml) * lda + k0 + c16 * 8, &As[(size_t)cb * 8]);
    }
#pragma unroll
    for (int i = 0; i < (TNv * 8) / 256; ++i) {
      const int cb = i * 256 + wid * 64;
      const int chunk = cb + lane;
      const int ml = chunk >> 3;
      const int c16 = (chunk & 7) ^ (ml & 7);
      gload16(Wz + (size_t)(bn + ml) * lda + k0 + c16 * 8, &Ws[(size_t)cb * 8]);
    }
    __syncthreads();

    bf16x8 af[2][MF], wf[2][NF];
#pragma unroll
    for (int kk = 0; kk < 2; ++kk) {
#pragma unroll
      for (int f = 0; f < MF; ++f) {
        const int ma = rowoff + f * 16 + lane15;
        const int ca = (kk * 4 + lgrp) ^ (ma & 7);
        af[kk][f] = *(const bf16x8*)&As[ma * 64 + ca * 8];
      }
#pragma unroll
      for (int f = 0; f < NF; ++f) {
        const int nb = wnoff + f * 16 + lane15;
        const int cw = (kk * 4 + lgrp) ^ (nb & 7);
        wf[kk][f] = *(const bf16x8*)&Ws[nb * 64 + cw * 8];
      }
    }
#pragma unroll
    for (int kk = 0; kk < 2; ++kk)
#pragma unroll
      for (int fm = 0; fm < MF; ++fm)
#pragma unroll
        for (int fn = 0; fn < NF; ++fn)
          acc[fm][fn] = __builtin_amdgcn_mfma_f32_16x16x32_bf16(
              af[kk][fm], wf[kk][fn], acc[fm][fn], 0, 0, 0);
  }

#pragma unroll
  for (int fm = 0; fm < MF; ++fm) {
#pragma unroll
    for (int fn = 0; fn < NF; ++fn) {
      const int n = bn + wnoff + fn * 16 + lane15;
      float bcol = 0.f;
      if (EPI == 2) bcol = bias[(n >> 1) + (n & 1) * 512];
      else if ((EPI == 1 || !BROW) && bias) bcol = bias[n];
#pragma unroll
      for (int r = 0; r < 4; ++r) {
        const int m = bm + rowoff + fm * 16 + lgrp * 4 + r;
        float val = acc[fm][fn][r];
        if (EPI == 1) {
          val += bcol;
          float p = __shfl_xor(val, 1);
          const int l = m & 2047, b = m >> 11;
          const int h = (n >> 5) & 15;
          if (n < 1024) {
            const int ch = n & 31, i2 = ch >> 1;
            const float cv = tab[l * 32 + i2], sv = tab[l * 32 + 16 + i2];
            const float o = (ch & 1) ? (p * sv + val * cv) : (val * cv - p * sv);
            const int dcol = (ch & 1) ? 16 + i2 : i2;
            if (n < 512)
              Qb[(((size_t)(b * 16 + h)) * 2048 + l) * 32 + dcol] =
                  bf16r(o * (0.1767766952966369f * 1.4426950408889634f));
            else
              Kb[(((size_t)(b * 16 + h)) * 2048 + l) * 32 + dcol] = bf16r(o);
          } else {
            Vb[(((size_t)(b * 16 + h)) * 2048 + l) * 32 + (n & 31)] = bf16r(val);
          }
        } else if (EPI == 2) {
          val += bcol;
          float p = __shfl_xor(val, 1);
          if (!(n & 1)) {
            float glu = val / (1.f + __expf(-p));
            Cb[(size_t)m * 512 + (n >> 1)] = bf16r(glu);
          }
        } else {
          val += BROW ? (bias ? bias[m] : 0.f) : bcol;
          if (RES) val += res[(size_t)m * N + n];
          if (GELU) val = gelu_fast(val);
          const size_t o = (size_t)z * sC + (size_t)m * ldC + n;
          if (OUTF) Cf[o] = val;
          if (OUTB) Cb[o] = bf16r(val);
        }
      }
    }
  }
}

// ================================================================ weight/src -> bf16 (11 segments)
struct CvtArgs {
  const float* s[11];
  ushort* d[11];
  int n[11];
  int pm[11];
};
__global__ __launch_bounds__(256) void cvt_all_k(CvtArgs a) {
  const int seg = blockIdx.y;
  const int n = a.n[seg];
  const int i = (blockIdx.x * 256 + threadIdx.x) * 8;
  if (i >= n) return;
  const float* s = a.s[seg] + i;
  float4 x = *(const float4*)s, y = *(const float4*)(s + 4);
  bf16x8 o;
  o[0] = (short)bf16r(x.x); o[1] = (short)bf16r(x.y);
  o[2] = (short)bf16r(x.z); o[3] = (short)bf16r(x.w);
  o[4] = (short)bf16r(y.x); o[5] = (short)bf16r(y.y);
  o[6] = (short)bf16r(y.z); o[7] = (short)bf16r(y.w);
  ushort* d = a.d[seg] + i;
  const int pm = a.pm[seg];
  if (pm == 1) {
    int cc = i >> 3;
    int row = cc >> 6, off = cc & 63;
    int nrow = (row < 512) ? row * 2 : (row - 512) * 2 + 1;
    d = a.d[seg] + (((size_t)nrow << 6) + off) * 8;
  } else if (pm >= 2) {
    d = a.d[seg] + (size_t)(i >> 9) * 1024 + (i & 511) + ((pm == 3) ? 512 : 0);
  }
  *(bf16x8*)d = o;
}

// ---------------------------------------------------------------- RoPE table + QKV bias gather + cat bias
__global__ void misc_k(float* __restrict__ tab, const float* __restrict__ bq,
                       const float* __restrict__ bk, const float* __restrict__ bv,
                       float* __restrict__ bqkv, const float* __restrict__ p2b,
                       const float* __restrict__ pw2b, float* __restrict__ bcat) {
  if (blockIdx.x < 128) {
    int t = blockIdx.x * 256 + threadIdx.x;
    int i = t & 15, l = t >> 4;
    float cv, sv;
    if (i < 8) {
      float inv0 = 1.0f / powf(10000.0f, (float)(2 * i) / 16.0f);
      float inv1 = 1.0f / powf(10000.0f, (float)(2 * i + 1) / 16.0f);
      cv = cosf((float)l * inv0);
      sv = cosf((float)l * inv1);
    } else {
      int ii = i - 8;
      float inv0 = 1.0f / powf(10000.0f, (float)(2 * ii) / 16.0f);
      float inv1 = 1.0f / powf(10000.0f, (float)(2 * ii + 1) / 16.0f);
      cv = sinf((float)l * inv0);
      sv = sinf((float)l * inv1);
    }
    tab[l * 32 + i] = cv;
    tab[l * 32 + 16 + i] = sv;
  } else {
    int i = threadIdx.x;
    bqkv[i] = bq[i];            bqkv[i + 256] = bq[i + 256];
    bqkv[512 + i] = bk[i];      bqkv[768 + i] = bk[i + 256];
    bqkv[1024 + i] = bv[i];     bqkv[1280 + i] = bv[i + 256];
    bcat[i] = p2b[i] + pw2b[i];
    bcat[i + 256] = p2b[i + 256] + pw2b[i + 256];
  }
}

// ---------------------------------------------------------------- transpose x0 f32 -> x0T bf16 (B,D,L)
__global__ __launch_bounds__(256) void transp_k(const float* __restrict__ x,
                                                ushort* __restrict__ xT) {
  __shared__ float t[32][33];
  const int b = blockIdx.z, l0 = blockIdx.x * 32, d0 = blockIdx.y * 32;
  const int tx = threadIdx.x & 31, ty = threadIdx.x >> 5;
#pragma unroll
  for (int i = 0; i < 4; ++i)
    t[ty + i * 8][tx] = x[((size_t)(b * L_ + l0 + ty + i * 8)) * D_ + d0 + tx];
  __syncthreads();
#pragma unroll
  for (int i = 0; i < 4; ++i)
    xT[((size_t)(b * D_ + d0 + ty + i * 8)) * L_ + l0 + tx] =
        bf16r(t[tx][ty + i * 8]);
}

// ---------------------------------------------------------------- combine proj split-K halves -> cat[:,0:512]
__global__ __launch_bounds__(256) void cmb_proj_k(const ushort* __restrict__ p,
                                                  const float* __restrict__ biasRow,
                                                  ushort* __restrict__ cat) {
  int t = blockIdx.x * 256 + threadIdx.x;
  int n4 = t & 127;
  int m = (t >> 7) & 2047;
  int zb = t >> 18;
  size_t i0 = ((size_t)(zb * 2) * 2048 + m) * 512 + n4 * 4;
  uint2 a = *(const uint2*)&p[i0];
  uint2 b = *(const uint2*)&p[i0 + (size_t)2048 * 512];
  float bm = biasRow[m];
  float o0 = bf2f(a.x & 0xffffu) + bf2f(b.x & 0xffffu) + bm;
  float o1 = bf2f(a.x >> 16) + bf2f(b.x >> 16) + bm;
  float o2 = bf2f(a.y & 0xffffu) + bf2f(b.y & 0xffffu) + bm;
  float o3 = bf2f(a.y >> 16) + bf2f(b.y >> 16) + bm;
  uint lo = (uint)bf16r(o0) | ((uint)bf16r(o1) << 16);
  uint hi = (uint)bf16r(o2) | ((uint)bf16r(o3) << 16);
  uint2 ov = {lo, hi};
  *(uint2*)&cat[((size_t)(zb * 2048 + m)) * 1024 + n4 * 4] = ov;
}

// ---------------------------------------------------------------- MFMA flash attention (r12 single-buffer form)
// 8 waves / 512 thr, 128 q/block; register prefetch of next tile overlaps
// compute; swapped QK^T; static shift slope*qg; region-specialized softmax;
// lsum via ones-MFMA; XCD-aware bid map.
__global__ __launch_bounds__(512, 4) void attn_mfma_k(const ushort* __restrict__ q,
                                                      const ushort* __restrict__ k,
                                                      const ushort* __restrict__ v,
                                                      ushort* __restrict__ ctx) {
  __shared__ __align__(16) ushort K_lds[4][130][8];
  __shared__ __align__(16) uint V_lds[32][68];
  const int tid = threadIdx.x;
  const int wid = tid >> 6, lane = tid & 63;
  const int s = lane >> 4, lr = lane & 15;
  const int bid = blockIdx.x;          // 512 blocks
  const int xcd = bid & 7, idx = bid >> 3;
  const int bh = xcd * 4 + (idx & 3);
  const int qt = idx >> 2;
  const int qb = qt * 128;
  const int h = bh & 15, bidx = bh >> 4;
  const float nslope = -exp2f(-0.5f * (float)h) * 1.4426950408889634f;
  const int qrow = qb + wid * 16 + lr;
  const float qgf = (float)qrow;
  const float cq = nslope * qgf;
  bf16x8 qa = *(const bf16x8*)&q[((size_t)bh * L_ + qrow) * HD_ + s * 8];

  bf16x8 vones;
#pragma unroll
  for (int i = 0; i < 8; ++i) vones[i] = (short)0x3F80;

  f32x4 acc0 = {0.f, 0.f, 0.f, 0.f}, acc1 = {0.f, 0.f, 0.f, 0.f};
  f32x4 accl = {0.f, 0.f, 0.f, 0.f};
  const ushort* kg = k + (size_t)bh * L_ * HD_;
  const ushort* vg = v + (size_t)bh * L_ * HD_;
  const int vslot = (lane & 48) + ((lane >> 1) & 3) * 4 + ((lane >> 3) & 1) * 2 + (lane & 1);
  const int kkey = tid >> 2, kslot = tid & 3;

  bf16x8 kreg;
  uint2 va, vb;
  {
    kreg = *(const bf16x8*)&kg[(size_t)kkey * HD_ + kslot * 8];
    const ushort* g0 = vg + (size_t)(2 * lane) * HD_ + wid * 4;
    va = *(const uint2*)g0;
    vb = *(const uint2*)(g0 + HD_);
  }

  for (int t0 = 0; t0 < L_; t0 += 128) {
    __syncthreads();
    *(bf16x8*)&K_lds[kslot][kkey][0] = kreg;
    V_lds[wid * 4 + 0][vslot] = __builtin_amdgcn_perm(vb.x, va.x, 0x05040100u);
    V_lds[wid * 4 + 1][vslot] = __builtin_amdgcn_perm(vb.x, va.x, 0x07060302u);
    V_lds[wid * 4 + 2][vslot] = __builtin_amdgcn_perm(vb.y, va.y, 0x05040100u);
    V_lds[wid * 4 + 3][vslot] = __builtin_amdgcn_perm(vb.y, va.y, 0x07060302u);
    if (t0 + 128 < L_) {
      kreg = *(const bf16x8*)&kg[(size_t)(t0 + 128 + kkey) * HD_ + kslot * 8];
      const ushort* g0 = vg + (size_t)(t0 + 128 + 2 * lane) * HD_ + wid * 4;
      va = *(const uint2*)g0;
      vb = *(const uint2*)(g0 + HD_);
    }
    asm volatile("s_waitcnt lgkmcnt(0)" ::: "memory");
    __builtin_amdgcn_s_barrier();
    __builtin_amdgcn_sched_barrier(0);

    f32x4 sc[8];
    __builtin_amdgcn_s_setprio(1);
#pragma unroll
    for (int c = 0; c < 8; ++c) {
      bf16x8 kf = *(const bf16x8*)&K_lds[s][c * 16 + lr][0];
      f32x4 zz = {0.f, 0.f, 0.f, 0.f};
      sc[c] = __builtin_amdgcn_mfma_f32_16x16x32_bf16(kf, qa, zz, 0, 0, 0);
    }
    __builtin_amdgcn_s_setprio(0);
    if (t0 < qb) {
      const float kb0 = (float)(t0 + s * 4);
#pragma unroll
      for (int c = 0; c < 8; ++c) {
        const float kc = kb0 + (float)(c * 16);
#pragma unroll
        for (int r = 0; r < 4; ++r)
          sc[c][r] = exp2f(fmaf(nslope, kc + (float)r, sc[c][r]));
      }
    } else if (t0 > qb) {
#pragma unroll
      for (int c = 0; c < 8; ++c)
#pragma unroll
        for (int r = 0; r < 4; ++r) sc[c][r] = exp2f(sc[c][r] + cq);
    } else {
      const float kb0 = (float)(t0 + s * 4);
#pragma unroll
      for (int c = 0; c < 8; ++c) {
        const float kc = kb0 + (float)(c * 16);
#pragma unroll
        for (int r = 0; r < 4; ++r) {
          float mn = fminf(kc + (float)r, qgf);
          sc[c][r] = exp2f(fmaf(nslope, mn, sc[c][r]));
        }
      }
    }
#pragma unroll
    for (int t = 0; t < 4; ++t) {
      uint w0 = __builtin_amdgcn_perm(__float_as_uint(sc[2 * t][1]),
                                      __float_as_uint(sc[2 * t][0]), 0x07060302u);
      uint w1 = __builtin_amdgcn_perm(__float_as_uint(sc[2 * t][3]),
                                      __float_as_uint(sc[2 * t][2]), 0x07060302u);
      uint w2 = __builtin_amdgcn_perm(__float_as_uint(sc[2 * t + 1][1]),
                                      __float_as_uint(sc[2 * t + 1][0]), 0x07060302u);
      uint w3 = __builtin_amdgcn_perm(__float_as_uint(sc[2 * t + 1][3]),
                                      __float_as_uint(sc[2 * t + 1][2]), 0x07060302u);
      u32x4 pw = {w0, w1, w2, w3};
      bf16x8 pf = __builtin_bit_cast(bf16x8, pw);
      bf16x8 v0 = *(const bf16x8*)&V_lds[lr][t * 16 + s * 4];
      bf16x8 v1 = *(const bf16x8*)&V_lds[16 + lr][t * 16 + s * 4];
      __builtin_amdgcn_s_setprio(1);
      acc0 = __builtin_amdgcn_mfma_f32_16x16x32_bf16(pf, v0, acc0, 0, 0, 0);
      acc1 = __builtin_amdgcn_mfma_f32_16x16x32_bf16(pf, v1, acc1, 0, 0, 0);
      accl = __builtin_amdgcn_mfma_f32_16x16x32_bf16(pf, vones, accl, 0, 0, 0);
      __builtin_amdgcn_s_setprio(0);
    }
  }
#pragma unroll
  for (int r = 0; r < 4; ++r) {
    float il = 1.f / accl[r];
    int qg2 = qb + wid * 16 + s * 4 + r;
    ushort* op = ctx + ((size_t)(bidx * L_ + qg2)) * D_ + h * HD_;
    op[lr] = bf16r(acc0[r] * il);
    op[16 + lr] = bf16r(acc1[r] * il);
  }
}

// ---------------------------------------------------------------- x0 = res + LN(x), xln_bf = LN(x0)
__global__ __launch_bounds__(64) void ln_res_ln_k(
    const float* __restrict__ x, const float* __restrict__ res,
    const float* __restrict__ g1, const float* __restrict__ b1,
    const float* __restrict__ g2, const float* __restrict__ b2,
    float* __restrict__ x0, ushort* __restrict__ xln) {
  int row = blockIdx.x, lane = threadIdx.x;
  const float* xr = x + (size_t)row * D_;
  float v[8];
  float s = 0.f, ss = 0.f;
#pragma unroll
  for (int i = 0; i < 8; ++i) {
    float t = xr[i * 64 + lane];
    v[i] = t; s += t; ss += t * t;
  }
  s = wsum(s); ss = wsum(ss);
  float mean = s * (1.f / 512.f);
  float rstd = rsqrtf(ss * (1.f / 512.f) - mean * mean + EPS_);
  float w[8];
  float s2 = 0.f, ss2 = 0.f;
#pragma unroll
  for (int i = 0; i < 8; ++i) {
    int idx = i * 64 + lane;
    float t = res[(size_t)row * D_ + idx] + (v[i] - mean) * rstd * g1[idx] + b1[idx];
    w[i] = t; s2 += t; ss2 += t * t;
  }
  s2 = wsum(s2); ss2 = wsum(ss2);
  float mean2 = s2 * (1.f / 512.f);
  float rstd2 = rsqrtf(ss2 * (1.f / 512.f) - mean2 * mean2 + EPS_);
#pragma unroll
  for (int i = 0; i < 8; ++i) {
    int idx = i * 64 + lane;
    x0[(size_t)row * D_ + idx] = w[i];
    xln[(size_t)row * D_ + idx] = bf16r((w[i] - mean2) * rstd2 * g2[idx] + b2[idx]);
  }
}

// ---------------------------------------------------------------- final LN over zA+zB+b2+y
__global__ __launch_bounds__(64) void ln2_k(const float* __restrict__ zA,
                                            const float* __restrict__ zB,
                                            const float* __restrict__ yres,
                                            const float* __restrict__ b2,
                                            const float* __restrict__ g,
                                            const float* __restrict__ bb,
                                            float* __restrict__ out) {
  int row = blockIdx.x, lane = threadIdx.x;
  const size_t base = (size_t)row * D_;
  float v[8];
  float s = 0.f, ss = 0.f;
#pragma unroll
  for (int i = 0; i < 8; ++i) {
    int idx = i * 64 + lane;
    float t = zA[base + idx] + zB[base + idx] + b2[idx] + yres[base + idx];
    v[i] = t; s += t; ss += t * t;
  }
  s = wsum(s); ss = wsum(ss);
  float mean = s * (1.f / 512.f);
  float rstd = rsqrtf(ss * (1.f / 512.f) - mean * mean + EPS_);
#pragma unroll
  for (int i = 0; i < 8; ++i) {
    int idx = i * 64 + lane;
    out[base + idx] = (v[i] - mean) * rstd * g[idx] + bb[idx];
  }
}

// ---------------------------------------------------------------- depthwise conv K=5 + bn + hardswish
__global__ __launch_bounds__(256) void convbn_k(
    const ushort* __restrict__ x, const float* __restrict__ w,
    const float* __restrict__ wb, const float* __restrict__ bng,
    const float* __restrict__ bnb, ushort* __restrict__ out) {
  int t = blockIdx.x * 256 + threadIdx.x;
  int c4 = t & 127;
  int l = (t >> 7) & 2047;
  int b = t >> 18;
  int d0 = c4 * 4;
  float accv[4] = {0.f, 0.f, 0.f, 0.f};
#pragma unroll
  for (int kt = 0; kt < 5; ++kt) {
    int ls = l + kt - 2;
    if (ls >= 0 && ls < L_) {
      uint2 xv = *(const uint2*)&x[((size_t)(b * L_ + ls)) * D_ + d0];
      float pv[4] = {bf2f(xv.x & 0xffffu), bf2f(xv.x >> 16),
                     bf2f(xv.y & 0xffffu), bf2f(xv.y >> 16)};
#pragma unroll
      for (int j = 0; j < 4; ++j) accv[j] += pv[j] * w[(d0 + j) * 5 + kt];
    }
  }
  const float bscale = rsqrtf(1.0f + EPS_);
  float po[4];
#pragma unroll
  for (int j = 0; j < 4; ++j) {
    int d = d0 + j;
    float vv = accv[j] + wb[d];
    vv = vv * (bng[d] * bscale) + bnb[d];
    float hs = fminf(fmaxf(vv + 3.f, 0.f), 6.f);
    po[j] = vv * hs * (1.f / 6.f);
  }
  uint lo = (uint)bf16r(po[0]) | ((uint)bf16r(po[1]) << 16);
  uint hi = (uint)bf16r(po[2]) | ((uint)bf16r(po[3]) << 16);
  uint2 o2 = {lo, hi};
  *(uint2*)&out[((size_t)(b * L_ + l)) * 1024 + d0] = o2;
}

// ================================================================ launcher
extern "C" void kernel_launch(void* const* d_in, const int* in_sizes, int n_in,
                              void* d_out, int out_size, void* d_ws, size_t ws_size,
                              hipStream_t stream) {
  const float* src    = (const float*)d_in[0];
  const float* Wq     = (const float*)d_in[1];
  const float* bq     = (const float*)d_in[2];
  const float* Wk     = (const float*)d_in[3];
  const float* bk     = (const float*)d_in[4];
  const float* Wv     = (const float*)d_in[5];
  const float* bv     = (const float*)d_in[6];
  const float* Wo     = (const float*)d_in[7];
  const float* bo     = (const float*)d_in[8];
  const float* ln_g   = (const float*)d_in[9];
  const float* ln_b   = (const float*)d_in[10];
  const float* pw1_w  = (const float*)d_in[11];
  const float* pw1_b  = (const float*)d_in[12];
  const float* dw_w   = (const float*)d_in[13];
  const float* dw_b   = (const float*)d_in[14];
  const float* bn_g   = (const float*)d_in[15];
  const float* bn_b   = (const float*)d_in[16];
  const float* pw2_w  = (const float*)d_in[17];
  const float* pw2_b  = (const float*)d_in[18];
  const float* proj_w = (const float*)d_in[19];
  const float* proj_b = (const float*)d_in[20];
  const float* proj2_w= (const float*)d_in[21];
  const float* proj2_b= (const float*)d_in[22];
  const float* W1     = (const float*)d_in[23];
  const float* b1     = (const float*)d_in[24];
  const float* W2     = (const float*)d_in[25];
  const float* b2     = (const float*)d_in[26];
  const float* n1_g   = (const float*)d_in[27];
  const float* n1_b   = (const float*)d_in[28];
  const float* n2_g   = (const float*)d_in[29];
  const float* n2_b   = (const float*)d_in[30];
  float* out = (float*)d_out;

  char* wsb = (char*)d_ws;
  const size_t MB1 = 1 << 20;
  // weights (bf16)
  ushort* wqkv = (ushort*)(wsb);                          // 1536x512
  ushort* wo_w = (ushort*)(wsb + 1536 * 1024);            // 512x512
  ushort* pw1w = (ushort*)(wsb + 2 * MB1);                // 1024x512 interleaved
  ushort* wcat = (ushort*)(wsb + 3 * MB1);                // 512x1024 [proj2|pw2]
  ushort* pjww = (ushort*)(wsb + 4 * MB1);                // 2048x2048
  ushort* w1w  = (ushort*)(wsb + 12 * MB1);               // 2048x512
  ushort* w2w  = (ushort*)(wsb + 14 * MB1);               // 512x2048
  float*  bqkv = (float*)(wsb + 16 * MB1);                // 1536 f32
  float*  bcat = (float*)(wsb + 16 * MB1 + 6144);         // 512 f32
  float*  tab  = (float*)(wsb + 16 * MB1 + 8192);         // L*32 f32
  // arena: A0 [17M,33M) | B0 [33M,45M) | C0 [45M,49M) | D0 [49M,57M)
  char* A0 = wsb + 17 * MB1;
  ushort* src_bf = (ushort*)A0;              // steps 1-3 (4MiB)
  ushort* pprt   = (ushort*)A0;              // step 10-10.5 (8MiB)
  ushort* ff_bf  = (ushort*)A0;              // steps 12-13 (16MiB)
  float*  x0     = (float*)(A0 + 8 * MB1);   // steps 6-11 (8MiB)
  char* B0 = A0 + 16 * MB1;
  ushort* Qb = (ushort*)B0;                  // steps 3-4
  ushort* Kb = (ushort*)(B0 + 4 * MB1);
  ushort* Vb = (ushort*)(B0 + 8 * MB1);
  ushort* glu_bf = (ushort*)B0;              // steps 8-9 (4MiB)
  ushort* xln_bf = (ushort*)(B0 + 8 * MB1);  // steps 6-8 (4MiB)
  ushort* cat_bf = (ushort*)(B0 + 4 * MB1);  // steps 9-11 (8MiB)
  float*  zprt   = (float*)B0;               // step 13-14 (16MiB)
  char* C0 = B0 + 12 * MB1;
  ushort* ctx_bf = (ushort*)C0;              // steps 4-5
  ushort* x0T    = (ushort*)C0;              // steps 7-10
  ushort* y_bf   = (ushort*)C0;              // steps 11-12
  char* D0 = C0 + 4 * MB1;
  float* attnout = (float*)D0;               // steps 5-6
  float* y       = (float*)D0;               // steps 11-14 (8MiB)

  dim3 blk(256);

  // 1. convert weights + src to bf16
  CvtArgs ca;
  for (int i = 0; i < 11; ++i) ca.pm[i] = 0;
  ca.s[0] = Wq;     ca.d[0] = wqkv;              ca.n[0] = 512 * 512;
  ca.s[1] = Wk;     ca.d[1] = wqkv + 512 * 512;  ca.n[1] = 512 * 512;
  ca.s[2] = Wv;     ca.d[2] = wqkv + 1024 * 512; ca.n[2] = 512 * 512;
  ca.s[3] = Wo;     ca.d[3] = wo_w;              ca.n[3] = 512 * 512;
  ca.s[4] = pw1_w;  ca.d[4] = pw1w;              ca.n[4] = 1024 * 512; ca.pm[4] = 1;
  ca.s[5] = pw2_w;  ca.d[5] = wcat;              ca.n[5] = 512 * 512;  ca.pm[5] = 3;
  ca.s[6] = proj_w; ca.d[6] = pjww;              ca.n[6] = 2048 * 2048;
  ca.s[7] = proj2_w;ca.d[7] = wcat;              ca.n[7] = 512 * 512;  ca.pm[7] = 2;
  ca.s[8] = W1;     ca.d[8] = w1w;               ca.n[8] = 2048 * 512;
  ca.s[9] = W2;     ca.d[9] = w2w;               ca.n[9] = 512 * 2048;
  ca.s[10]= src;    ca.d[10]= src_bf;            ca.n[10]= BL_ * D_;
  cvt_all_k<<<dim3(2048, 11), blk, 0, stream>>>(ca);
  misc_k<<<dim3(129), blk, 0, stream>>>(tab, bq, bk, bv, bqkv, proj2_b, pw2_b, bcat);

  // 3. fused QKV + bias + RoPE
  gemm_bf_k<64,128,1,0,0,0,0,0,0><<<dim3(12, 64), blk, 0, stream>>>(
      src_bf, wqkv, bqkv, nullptr, nullptr, nullptr,
      BL_, 1536, 512, 0, 0, 1536, tab, Qb, Kb, Vb);

  // 4. attention (r12 single-buffer form)
  attn_mfma_k<<<dim3(512), dim3(512), 0, stream>>>(Qb, Kb, Vb, ctx_bf);

  // 5. Wo  ((32,64) tile: 1024 blocks, 16 waves/CU)
  gemm_bf_k<32,64,0,0,0,0,1,0,0><<<dim3(8, 128), blk, 0, stream>>>(
      ctx_bf, wo_w, bo, nullptr, attnout, nullptr,
      BL_, 512, 512, 0, 0, 512, nullptr, nullptr, nullptr, nullptr);

  // 6. x0 = src + LN(attnout); xln_bf = LN(x0)
  ln_res_ln_k<<<BL_, 64, 0, stream>>>(attnout, src, n1_g, n1_b, ln_g, ln_b,
                                      x0, xln_bf);

  // 7. transpose x0 -> x0T bf16
  transp_k<<<dim3(64, 16, 2), blk, 0, stream>>>(x0, x0T);

  // 8. pw1 + fused GLU -> glu_bf
  gemm_bf_k<64,128,2,0,0,0,0,1,0><<<dim3(8, 64), blk, 0, stream>>>(
      xln_bf, pw1w, pw1_b, nullptr, nullptr, glu_bf,
      BL_, 1024, 512, 0, 0, 512, nullptr, nullptr, nullptr, nullptr);

  // 9. conv + bn + hswish -> cat[:,512:1024]
  convbn_k<<<(B_ * L_ * (D_ / 4)) / 256, blk, 0, stream>>>(
      glu_bf, dw_w, dw_b, bn_g, bn_b, cat_bf + 512);

  // 10. proj split-K x2 ((32,64): 2048 blocks) -> pprt, 10.5 combine
  gemm_bf_k<32,64,0,0,0,0,0,1,1><<<dim3(8, 64, 4), blk, 0, stream>>>(
      pjww, x0T, nullptr, nullptr, nullptr, pprt,
      2048, 512, 1024, (long)512 * 2048, (long)2048 * 512, 512,
      nullptr, nullptr, nullptr, nullptr);
  cmb_proj_k<<<dim3(2048), blk, 0, stream>>>(pprt, proj_b, cat_bf);

  // 11. fused (proj2 + pw2) cat-GEMM ((32,64): 1024 blocks)
  gemm_bf_k<32,64,0,0,0,1,1,1,0><<<dim3(8, 128), blk, 0, stream>>>(
      cat_bf, wcat, bcat, x0, y, y_bf,
      BL_, 512, 1024, 0, 0, 512, nullptr, nullptr, nullptr, nullptr);

  // 12. W1 + fast-gelu -> ff_bf
  gemm_bf_k<64,128,0,0,1,0,0,1,0><<<dim3(16, 64), blk, 0, stream>>>(
      y_bf, w1w, b1, nullptr, nullptr, ff_bf,
      BL_, 2048, 512, 0, 0, 2048, nullptr, nullptr, nullptr, nullptr);

  // 13. W2 split-K x2 ((32,64): 2048 blocks) -> zprt f32
  gemm_bf_k<32,64,0,0,0,0,1,0,1><<<dim3(8, 128, 2), blk, 0, stream>>>(
      ff_bf, w2w, nullptr, nullptr, zprt, nullptr,
      BL_, 512, 1024, 0, (long)BL_ * 512, 512,
      nullptr, nullptr, nullptr, nullptr);

  // 14. final LN over zA+zB+b2+y
  ln2_k<<<BL_, 64, 0, stream>>>(zprt, zprt + (size_t)BL_ * 512, y, b2,
                                n2_g, n2_b, out);
}

// Round 17
// 219.840 us; speedup vs baseline: 1.0298x; 1.0298x over previous
//
#include <hip/hip_runtime.h>
#include <math.h>

#define B_ 2
#define L_ 2048
#define D_ 512
#define H_ 16
#define HD_ 32
#define FF_ 2048
#define BL_ 4096
#define EPS_ 1e-5f

typedef unsigned short ushort;
typedef unsigned int uint;
typedef __attribute__((ext_vector_type(8))) short bf16x8;
typedef __attribute__((ext_vector_type(4))) float f32x4;
typedef __attribute__((ext_vector_type(4))) uint u32x4;

__device__ __forceinline__ ushort bf16r(float f) {
  uint u = __float_as_uint(f);
  uint r = (u + 0x7FFFu + ((u >> 16) & 1u)) >> 16;
  return (ushort)r;
}
__device__ __forceinline__ float bf2f(uint u) { return __uint_as_float(u << 16); }

__device__ __forceinline__ float wsum(float v) {
#pragma unroll
  for (int o = 32; o; o >>= 1) v += __shfl_xor(v, o);
  return v;
}

// fast tanh-form GELU
__device__ __forceinline__ float gelu_fast(float x) {
  float t = x + 0.044715f * x * x * x;
  float e = exp2f(fminf(2.302118131f * t, 80.f));
  return x * e / (1.f + e);
}

__device__ __forceinline__ void gload16(const void* g, void* l) {
  __builtin_amdgcn_global_load_lds(
      (const __attribute__((address_space(1))) void*)g,
      (__attribute__((address_space(3))) void*)l, 16, 0, 0);
}

// ================================================================ bf16 MFMA GEMM
// C[m,n] = epi( sum_k A[m,k] * W[n,k] );  SPK=1: split-K x2 over z.
// tile classes (256 thr): (64,128) 4 waves x 64x32; (64,64) 4 waves x 32x32
template <int TMv, int TNv, int EPI, int BROW, int GELU, int RES, int OUTF, int OUTB, int SPK>
__global__ __launch_bounds__(256, 2) void gemm_bf_k(
    const ushort* __restrict__ A, const ushort* __restrict__ W,
    const float* __restrict__ bias, const float* __restrict__ res,
    float* __restrict__ Cf, ushort* __restrict__ Cb,
    const int M, const int N, const int Kd, const long sW, const long sC,
    const int ldC,
    const float* __restrict__ tab, ushort* __restrict__ Qb,
    ushort* __restrict__ Kb, ushort* __restrict__ Vb) {
  constexpr int MF = (TMv == 128) ? 4 : ((TNv == 128) ? 4 : 2);
  constexpr int NF = (TNv == 128) ? ((TMv == 128) ? 4 : 2) : 2;
  __shared__ __align__(16) ushort As[TMv * 64];
  __shared__ __align__(16) ushort Ws[TNv * 64];
  const int tid = threadIdx.x;
  const int wid = tid >> 6, lane = tid & 63;
  const int lane15 = lane & 15, lgrp = lane >> 4;
  const int rowoff = (TMv == 128) ? (wid >> 1) * 64
                                  : ((TNv == 64) ? (wid >> 1) * 32 : 0);
  const int wnoff = (TMv == 128) ? (wid & 1) * 64
                                 : ((TNv == 128) ? wid * 32 : (wid & 1) * 32);
  const int bm = blockIdx.y * TMv, bn = blockIdx.x * TNv;
  const int z = blockIdx.z;
  const int lda = SPK ? (Kd << 1) : Kd;
  const int kh = SPK ? (z & 1) : 0;
  const int zb = SPK ? (z >> 1) : z;
  const ushort* Az = A + (size_t)kh * Kd;
  const ushort* Wz = W + (size_t)zb * sW + (size_t)kh * Kd;

  f32x4 acc[MF][NF];
#pragma unroll
  for (int i = 0; i < MF; ++i)
#pragma unroll
    for (int j = 0; j < NF; ++j) acc[i][j] = (f32x4){0.f, 0.f, 0.f, 0.f};

  for (int k0 = 0; k0 < Kd; k0 += 64) {
    __syncthreads();
#pragma unroll
    for (int i = 0; i < TMv / 32; ++i) {
      const int cb = i * 256 + wid * 64;
      const int chunk = cb + lane;
      const int ml = chunk >> 3;
      const int c16 = (chunk & 7) ^ (ml & 7);
      gload16(Az + (size_t)(bm + ml) * lda + k0 + c16 * 8, &As[(size_t)cb * 8]);
    }
#pragma unroll
    for (int i = 0; i < TNv / 32; ++i) {
      const int cb = i * 256 + wid * 64;
      const int chunk = cb + lane;
      const int ml = chunk >> 3;
      const int c16 = (chunk & 7) ^ (ml & 7);
      gload16(Wz + (size_t)(bn + ml) * lda + k0 + c16 * 8, &Ws[(size_t)cb * 8]);
    }
    __syncthreads();

    bf16x8 af[2][MF], wf[2][NF];
#pragma unroll
    for (int kk = 0; kk < 2; ++kk) {
#pragma unroll
      for (int f = 0; f < MF; ++f) {
        const int ma = rowoff + f * 16 + lane15;
        const int ca = (kk * 4 + lgrp) ^ (ma & 7);
        af[kk][f] = *(const bf16x8*)&As[ma * 64 + ca * 8];
      }
#pragma unroll
      for (int f = 0; f < NF; ++f) {
        const int nb = wnoff + f * 16 + lane15;
        const int cw = (kk * 4 + lgrp) ^ (nb & 7);
        wf[kk][f] = *(const bf16x8*)&Ws[nb * 64 + cw * 8];
      }
    }
#pragma unroll
    for (int kk = 0; kk < 2; ++kk)
#pragma unroll
      for (int fm = 0; fm < MF; ++fm)
#pragma unroll
        for (int fn = 0; fn < NF; ++fn)
          acc[fm][fn] = __builtin_amdgcn_mfma_f32_16x16x32_bf16(
              af[kk][fm], wf[kk][fn], acc[fm][fn], 0, 0, 0);
  }

#pragma unroll
  for (int fm = 0; fm < MF; ++fm) {
#pragma unroll
    for (int fn = 0; fn < NF; ++fn) {
      const int n = bn + wnoff + fn * 16 + lane15;
      float bcol = 0.f;
      if (EPI == 2) bcol = bias[(n >> 1) + (n & 1) * 512];
      else if ((EPI == 1 || !BROW) && bias) bcol = bias[n];
#pragma unroll
      for (int r = 0; r < 4; ++r) {
        const int m = bm + rowoff + fm * 16 + lgrp * 4 + r;
        float val = acc[fm][fn][r];
        if (EPI == 1) {
          val += bcol;
          float p = __shfl_xor(val, 1);
          const int l = m & 2047, b = m >> 11;
          const int h = (n >> 5) & 15;
          if (n < 1024) {
            const int ch = n & 31, i2 = ch >> 1;
            const float cv = tab[l * 32 + i2], sv = tab[l * 32 + 16 + i2];
            const float o = (ch & 1) ? (p * sv + val * cv) : (val * cv - p * sv);
            const int dcol = (ch & 1) ? 16 + i2 : i2;
            if (n < 512)
              Qb[(((size_t)(b * 16 + h)) * 2048 + l) * 32 + dcol] =
                  bf16r(o * (0.1767766952966369f * 1.4426950408889634f));
            else
              Kb[(((size_t)(b * 16 + h)) * 2048 + l) * 32 + dcol] = bf16r(o);
          } else {
            Vb[(((size_t)(b * 16 + h)) * 2048 + l) * 32 + (n & 31)] = bf16r(val);
          }
        } else if (EPI == 2) {
          val += bcol;
          float p = __shfl_xor(val, 1);
          if (!(n & 1)) {
            float glu = val / (1.f + __expf(-p));
            Cb[(size_t)m * 512 + (n >> 1)] = bf16r(glu);
          }
        } else {
          val += BROW ? (bias ? bias[m] : 0.f) : bcol;
          if (RES) val += res[(size_t)m * N + n];
          if (GELU) val = gelu_fast(val);
          const size_t o = (size_t)z * sC + (size_t)m * ldC + n;
          if (OUTF) Cf[o] = val;
          if (OUTB) Cb[o] = bf16r(val);
        }
      }
    }
  }
}

// ================================================================ weight/src -> bf16 (11 segments)
struct CvtArgs {
  const float* s[11];
  ushort* d[11];
  int n[11];
  int pm[11];
};
__global__ __launch_bounds__(256) void cvt_all_k(CvtArgs a) {
  const int seg = blockIdx.y;
  const int n = a.n[seg];
  const int i = (blockIdx.x * 256 + threadIdx.x) * 8;
  if (i >= n) return;
  const float* s = a.s[seg] + i;
  float4 x = *(const float4*)s, y = *(const float4*)(s + 4);
  bf16x8 o;
  o[0] = (short)bf16r(x.x); o[1] = (short)bf16r(x.y);
  o[2] = (short)bf16r(x.z); o[3] = (short)bf16r(x.w);
  o[4] = (short)bf16r(y.x); o[5] = (short)bf16r(y.y);
  o[6] = (short)bf16r(y.z); o[7] = (short)bf16r(y.w);
  ushort* d = a.d[seg] + i;
  const int pm = a.pm[seg];
  if (pm == 1) {
    int cc = i >> 3;
    int row = cc >> 6, off = cc & 63;
    int nrow = (row < 512) ? row * 2 : (row - 512) * 2 + 1;
    d = a.d[seg] + (((size_t)nrow << 6) + off) * 8;
  } else if (pm >= 2) {
    d = a.d[seg] + (size_t)(i >> 9) * 1024 + (i & 511) + ((pm == 3) ? 512 : 0);
  }
  *(bf16x8*)d = o;
}

// ---------------------------------------------------------------- RoPE table + QKV bias gather + cat bias
__global__ void misc_k(float* __restrict__ tab, const float* __restrict__ bq,
                       const float* __restrict__ bk, const float* __restrict__ bv,
                       float* __restrict__ bqkv, const float* __restrict__ p2b,
                       const float* __restrict__ pw2b, float* __restrict__ bcat) {
  if (blockIdx.x < 128) {
    int t = blockIdx.x * 256 + threadIdx.x;
    int i = t & 15, l = t >> 4;
    float cv, sv;
    if (i < 8) {
      float inv0 = 1.0f / powf(10000.0f, (float)(2 * i) / 16.0f);
      float inv1 = 1.0f / powf(10000.0f, (float)(2 * i + 1) / 16.0f);
      cv = cosf((float)l * inv0);
      sv = cosf((float)l * inv1);
    } else {
      int ii = i - 8;
      float inv0 = 1.0f / powf(10000.0f, (float)(2 * ii) / 16.0f);
      float inv1 = 1.0f / powf(10000.0f, (float)(2 * ii + 1) / 16.0f);
      cv = sinf((float)l * inv0);
      sv = sinf((float)l * inv1);
    }
    tab[l * 32 + i] = cv;
    tab[l * 32 + 16 + i] = sv;
  } else {
    int i = threadIdx.x;
    bqkv[i] = bq[i];            bqkv[i + 256] = bq[i + 256];
    bqkv[512 + i] = bk[i];      bqkv[768 + i] = bk[i + 256];
    bqkv[1024 + i] = bv[i];     bqkv[1280 + i] = bv[i + 256];
    bcat[i] = p2b[i] + pw2b[i];
    bcat[i + 256] = p2b[i + 256] + pw2b[i + 256];
  }
}

// ---------------------------------------------------------------- transpose x0 f32 -> x0T bf16 (B,D,L)
__global__ __launch_bounds__(256) void transp_k(const float* __restrict__ x,
                                                ushort* __restrict__ xT) {
  __shared__ float t[32][33];
  const int b = blockIdx.z, l0 = blockIdx.x * 32, d0 = blockIdx.y * 32;
  const int tx = threadIdx.x & 31, ty = threadIdx.x >> 5;
#pragma unroll
  for (int i = 0; i < 4; ++i)
    t[ty + i * 8][tx] = x[((size_t)(b * L_ + l0 + ty + i * 8)) * D_ + d0 + tx];
  __syncthreads();
#pragma unroll
  for (int i = 0; i < 4; ++i)
    xT[((size_t)(b * D_ + d0 + ty + i * 8)) * L_ + l0 + tx] =
        bf16r(t[tx][ty + i * 8]);
}

// ---------------------------------------------------------------- combine proj split-K halves -> cat[:,0:512]
__global__ __launch_bounds__(256) void cmb_proj_k(const ushort* __restrict__ p,
                                                  const float* __restrict__ biasRow,
                                                  ushort* __restrict__ cat) {
  int t = blockIdx.x * 256 + threadIdx.x;
  int n4 = t & 127;
  int m = (t >> 7) & 2047;
  int zb = t >> 18;
  size_t i0 = ((size_t)(zb * 2) * 2048 + m) * 512 + n4 * 4;
  uint2 a = *(const uint2*)&p[i0];
  uint2 b = *(const uint2*)&p[i0 + (size_t)2048 * 512];
  float bm = biasRow[m];
  float o0 = bf2f(a.x & 0xffffu) + bf2f(b.x & 0xffffu) + bm;
  float o1 = bf2f(a.x >> 16) + bf2f(b.x >> 16) + bm;
  float o2 = bf2f(a.y & 0xffffu) + bf2f(b.y & 0xffffu) + bm;
  float o3 = bf2f(a.y >> 16) + bf2f(b.y >> 16) + bm;
  uint lo = (uint)bf16r(o0) | ((uint)bf16r(o1) << 16);
  uint hi = (uint)bf16r(o2) | ((uint)bf16r(o3) << 16);
  uint2 ov = {lo, hi};
  *(uint2*)&cat[((size_t)(zb * 2048 + m)) * 1024 + n4 * 4] = ov;
}

// ---------------------------------------------------------------- MFMA flash attention (r12 single-buffer form)
// K_lds key-dim padded 130->132: plane stride 132*16B == 16 words (mod 32),
// reducing K-write bank aliasing 4-way -> 2-way (free).
__global__ __launch_bounds__(512, 4) void attn_mfma_k(const ushort* __restrict__ q,
                                                      const ushort* __restrict__ k,
                                                      const ushort* __restrict__ v,
                                                      ushort* __restrict__ ctx) {
  __shared__ __align__(16) ushort K_lds[4][132][8];
  __shared__ __align__(16) uint V_lds[32][68];
  const int tid = threadIdx.x;
  const int wid = tid >> 6, lane = tid & 63;
  const int s = lane >> 4, lr = lane & 15;
  const int bid = blockIdx.x;          // 512 blocks
  const int xcd = bid & 7, idx = bid >> 3;
  const int bh = xcd * 4 + (idx & 3);
  const int qt = idx >> 2;
  const int qb = qt * 128;
  const int h = bh & 15, bidx = bh >> 4;
  const float nslope = -exp2f(-0.5f * (float)h) * 1.4426950408889634f;
  const int qrow = qb + wid * 16 + lr;
  const float qgf = (float)qrow;
  const float cq = nslope * qgf;
  bf16x8 qa = *(const bf16x8*)&q[((size_t)bh * L_ + qrow) * HD_ + s * 8];

  bf16x8 vones;
#pragma unroll
  for (int i = 0; i < 8; ++i) vones[i] = (short)0x3F80;

  f32x4 acc0 = {0.f, 0.f, 0.f, 0.f}, acc1 = {0.f, 0.f, 0.f, 0.f};
  f32x4 accl = {0.f, 0.f, 0.f, 0.f};
  const ushort* kg = k + (size_t)bh * L_ * HD_;
  const ushort* vg = v + (size_t)bh * L_ * HD_;
  const int vslot = (lane & 48) + ((lane >> 1) & 3) * 4 + ((lane >> 3) & 1) * 2 + (lane & 1);
  const int kkey = tid >> 2, kslot = tid & 3;

  bf16x8 kreg;
  uint2 va, vb;
  {
    kreg = *(const bf16x8*)&kg[(size_t)kkey * HD_ + kslot * 8];
    const ushort* g0 = vg + (size_t)(2 * lane) * HD_ + wid * 4;
    va = *(const uint2*)g0;
    vb = *(const uint2*)(g0 + HD_);
  }

  for (int t0 = 0; t0 < L_; t0 += 128) {
    __syncthreads();
    *(bf16x8*)&K_lds[kslot][kkey][0] = kreg;
    V_lds[wid * 4 + 0][vslot] = __builtin_amdgcn_perm(vb.x, va.x, 0x05040100u);
    V_lds[wid * 4 + 1][vslot] = __builtin_amdgcn_perm(vb.x, va.x, 0x07060302u);
    V_lds[wid * 4 + 2][vslot] = __builtin_amdgcn_perm(vb.y, va.y, 0x05040100u);
    V_lds[wid * 4 + 3][vslot] = __builtin_amdgcn_perm(vb.y, va.y, 0x07060302u);
    if (t0 + 128 < L_) {
      kreg = *(const bf16x8*)&kg[(size_t)(t0 + 128 + kkey) * HD_ + kslot * 8];
      const ushort* g0 = vg + (size_t)(t0 + 128 + 2 * lane) * HD_ + wid * 4;
      va = *(const uint2*)g0;
      vb = *(const uint2*)(g0 + HD_);
    }
    asm volatile("s_waitcnt lgkmcnt(0)" ::: "memory");
    __builtin_amdgcn_s_barrier();
    __builtin_amdgcn_sched_barrier(0);

    f32x4 sc[8];
    __builtin_amdgcn_s_setprio(1);
#pragma unroll
    for (int c = 0; c < 8; ++c) {
      bf16x8 kf = *(const bf16x8*)&K_lds[s][c * 16 + lr][0];
      f32x4 zz = {0.f, 0.f, 0.f, 0.f};
      sc[c] = __builtin_amdgcn_mfma_f32_16x16x32_bf16(kf, qa, zz, 0, 0, 0);
    }
    __builtin_amdgcn_s_setprio(0);
    if (t0 < qb) {
      const float kb0 = (float)(t0 + s * 4);
#pragma unroll
      for (int c = 0; c < 8; ++c) {
        const float kc = kb0 + (float)(c * 16);
#pragma unroll
        for (int r = 0; r < 4; ++r)
          sc[c][r] = exp2f(fmaf(nslope, kc + (float)r, sc[c][r]));
      }
    } else if (t0 > qb) {
#pragma unroll
      for (int c = 0; c < 8; ++c)
#pragma unroll
        for (int r = 0; r < 4; ++r) sc[c][r] = exp2f(sc[c][r] + cq);
    } else {
      const float kb0 = (float)(t0 + s * 4);
#pragma unroll
      for (int c = 0; c < 8; ++c) {
        const float kc = kb0 + (float)(c * 16);
#pragma unroll
        for (int r = 0; r < 4; ++r) {
          float mn = fminf(kc + (float)r, qgf);
          sc[c][r] = exp2f(fmaf(nslope, mn, sc[c][r]));
        }
      }
    }
#pragma unroll
    for (int t = 0; t < 4; ++t) {
      uint w0 = __builtin_amdgcn_perm(__float_as_uint(sc[2 * t][1]),
                                      __float_as_uint(sc[2 * t][0]), 0x07060302u);
      uint w1 = __builtin_amdgcn_perm(__float_as_uint(sc[2 * t][3]),
                                      __float_as_uint(sc[2 * t][2]), 0x07060302u);
      uint w2 = __builtin_amdgcn_perm(__float_as_uint(sc[2 * t + 1][1]),
                                      __float_as_uint(sc[2 * t + 1][0]), 0x07060302u);
      uint w3 = __builtin_amdgcn_perm(__float_as_uint(sc[2 * t + 1][3]),
                                      __float_as_uint(sc[2 * t + 1][2]), 0x07060302u);
      u32x4 pw = {w0, w1, w2, w3};
      bf16x8 pf = __builtin_bit_cast(bf16x8, pw);
      bf16x8 v0 = *(const bf16x8*)&V_lds[lr][t * 16 + s * 4];
      bf16x8 v1 = *(const bf16x8*)&V_lds[16 + lr][t * 16 + s * 4];
      __builtin_amdgcn_s_setprio(1);
      acc0 = __builtin_amdgcn_mfma_f32_16x16x32_bf16(pf, v0, acc0, 0, 0, 0);
      acc1 = __builtin_amdgcn_mfma_f32_16x16x32_bf16(pf, v1, acc1, 0, 0, 0);
      accl = __builtin_amdgcn_mfma_f32_16x16x32_bf16(pf, vones, accl, 0, 0, 0);
      __builtin_amdgcn_s_setprio(0);
    }
  }
#pragma unroll
  for (int r = 0; r < 4; ++r) {
    float il = 1.f / accl[r];
    int qg2 = qb + wid * 16 + s * 4 + r;
    ushort* op = ctx + ((size_t)(bidx * L_ + qg2)) * D_ + h * HD_;
    op[lr] = bf16r(acc0[r] * il);
    op[16 + lr] = bf16r(acc1[r] * il);
  }
}

// ---------------------------------------------------------------- x0 = res + LN(x), xln_bf = LN(x0)
__global__ __launch_bounds__(64) void ln_res_ln_k(
    const float* __restrict__ x, const float* __restrict__ res,
    const float* __restrict__ g1, const float* __restrict__ b1,
    const float* __restrict__ g2, const float* __restrict__ b2,
    float* __restrict__ x0, ushort* __restrict__ xln) {
  int row = blockIdx.x, lane = threadIdx.x;
  const float* xr = x + (size_t)row * D_;
  float v[8];
  float s = 0.f, ss = 0.f;
#pragma unroll
  for (int i = 0; i < 8; ++i) {
    float t = xr[i * 64 + lane];
    v[i] = t; s += t; ss += t * t;
  }
  s = wsum(s); ss = wsum(ss);
  float mean = s * (1.f / 512.f);
  float rstd = rsqrtf(ss * (1.f / 512.f) - mean * mean + EPS_);
  float w[8];
  float s2 = 0.f, ss2 = 0.f;
#pragma unroll
  for (int i = 0; i < 8; ++i) {
    int idx = i * 64 + lane;
    float t = res[(size_t)row * D_ + idx] + (v[i] - mean) * rstd * g1[idx] + b1[idx];
    w[i] = t; s2 += t; ss2 += t * t;
  }
  s2 = wsum(s2); ss2 = wsum(ss2);
  float mean2 = s2 * (1.f / 512.f);
  float rstd2 = rsqrtf(ss2 * (1.f / 512.f) - mean2 * mean2 + EPS_);
#pragma unroll
  for (int i = 0; i < 8; ++i) {
    int idx = i * 64 + lane;
    x0[(size_t)row * D_ + idx] = w[i];
    xln[(size_t)row * D_ + idx] = bf16r((w[i] - mean2) * rstd2 * g2[idx] + b2[idx]);
  }
}

// ---------------------------------------------------------------- final LN over zA+zB+b2+y
__global__ __launch_bounds__(64) void ln2_k(const float* __restrict__ zA,
                                            const float* __restrict__ zB,
                                            const float* __restrict__ yres,
                                            const float* __restrict__ b2,
                                            const float* __restrict__ g,
                                            const float* __restrict__ bb,
                                            float* __restrict__ out) {
  int row = blockIdx.x, lane = threadIdx.x;
  const size_t base = (size_t)row * D_;
  float v[8];
  float s = 0.f, ss = 0.f;
#pragma unroll
  for (int i = 0; i < 8; ++i) {
    int idx = i * 64 + lane;
    float t = zA[base + idx] + zB[base + idx] + b2[idx] + yres[base + idx];
    v[i] = t; s += t; ss += t * t;
  }
  s = wsum(s); ss = wsum(ss);
  float mean = s * (1.f / 512.f);
  float rstd = rsqrtf(ss * (1.f / 512.f) - mean * mean + EPS_);
#pragma unroll
  for (int i = 0; i < 8; ++i) {
    int idx = i * 64 + lane;
    out[base + idx] = (v[i] - mean) * rstd * g[idx] + bb[idx];
  }
}

// ---------------------------------------------------------------- depthwise conv K=5 + bn + hardswish
__global__ __launch_bounds__(256) void convbn_k(
    const ushort* __restrict__ x, const float* __restrict__ w,
    const float* __restrict__ wb, const float* __restrict__ bng,
    const float* __restrict__ bnb, ushort* __restrict__ out) {
  int t = blockIdx.x * 256 + threadIdx.x;
  int c4 = t & 127;
  int l = (t >> 7) & 2047;
  int b = t >> 18;
  int d0 = c4 * 4;
  float accv[4] = {0.f, 0.f, 0.f, 0.f};
#pragma unroll
  for (int kt = 0; kt < 5; ++kt) {
    int ls = l + kt - 2;
    if (ls >= 0 && ls < L_) {
      uint2 xv = *(const uint2*)&x[((size_t)(b * L_ + ls)) * D_ + d0];
      float pv[4] = {bf2f(xv.x & 0xffffu), bf2f(xv.x >> 16),
                     bf2f(xv.y & 0xffffu), bf2f(xv.y >> 16)};
#pragma unroll
      for (int j = 0; j < 4; ++j) accv[j] += pv[j] * w[(d0 + j) * 5 + kt];
    }
  }
  const float bscale = rsqrtf(1.0f + EPS_);
  float po[4];
#pragma unroll
  for (int j = 0; j < 4; ++j) {
    int d = d0 + j;
    float vv = accv[j] + wb[d];
    vv = vv * (bng[d] * bscale) + bnb[d];
    float hs = fminf(fmaxf(vv + 3.f, 0.f), 6.f);
    po[j] = vv * hs * (1.f / 6.f);
  }
  uint lo = (uint)bf16r(po[0]) | ((uint)bf16r(po[1]) << 16);
  uint hi = (uint)bf16r(po[2]) | ((uint)bf16r(po[3]) << 16);
  uint2 o2 = {lo, hi};
  *(uint2*)&out[((size_t)(b * L_ + l)) * 1024 + d0] = o2;
}

// ================================================================ launcher
extern "C" void kernel_launch(void* const* d_in, const int* in_sizes, int n_in,
                              void* d_out, int out_size, void* d_ws, size_t ws_size,
                              hipStream_t stream) {
  const float* src    = (const float*)d_in[0];
  const float* Wq     = (const float*)d_in[1];
  const float* bq     = (const float*)d_in[2];
  const float* Wk     = (const float*)d_in[3];
  const float* bk     = (const float*)d_in[4];
  const float* Wv     = (const float*)d_in[5];
  const float* bv     = (const float*)d_in[6];
  const float* Wo     = (const float*)d_in[7];
  const float* bo     = (const float*)d_in[8];
  const float* ln_g   = (const float*)d_in[9];
  const float* ln_b   = (const float*)d_in[10];
  const float* pw1_w  = (const float*)d_in[11];
  const float* pw1_b  = (const float*)d_in[12];
  const float* dw_w   = (const float*)d_in[13];
  const float* dw_b   = (const float*)d_in[14];
  const float* bn_g   = (const float*)d_in[15];
  const float* bn_b   = (const float*)d_in[16];
  const float* pw2_w  = (const float*)d_in[17];
  const float* pw2_b  = (const float*)d_in[18];
  const float* proj_w = (const float*)d_in[19];
  const float* proj_b = (const float*)d_in[20];
  const float* proj2_w= (const float*)d_in[21];
  const float* proj2_b= (const float*)d_in[22];
  const float* W1     = (const float*)d_in[23];
  const float* b1     = (const float*)d_in[24];
  const float* W2     = (const float*)d_in[25];
  const float* b2     = (const float*)d_in[26];
  const float* n1_g   = (const float*)d_in[27];
  const float* n1_b   = (const float*)d_in[28];
  const float* n2_g   = (const float*)d_in[29];
  const float* n2_b   = (const float*)d_in[30];
  float* out = (float*)d_out;

  char* wsb = (char*)d_ws;
  const size_t MB1 = 1 << 20;
  // weights (bf16)
  ushort* wqkv = (ushort*)(wsb);                          // 1536x512
  ushort* wo_w = (ushort*)(wsb + 1536 * 1024);            // 512x512
  ushort* pw1w = (ushort*)(wsb + 2 * MB1);                // 1024x512 interleaved
  ushort* wcat = (ushort*)(wsb + 3 * MB1);                // 512x1024 [proj2|pw2]
  ushort* pjww = (ushort*)(wsb + 4 * MB1);                // 2048x2048
  ushort* w1w  = (ushort*)(wsb + 12 * MB1);               // 2048x512
  ushort* w2w  = (ushort*)(wsb + 14 * MB1);               // 512x2048
  float*  bqkv = (float*)(wsb + 16 * MB1);                // 1536 f32
  float*  bcat = (float*)(wsb + 16 * MB1 + 6144);         // 512 f32
  float*  tab  = (float*)(wsb + 16 * MB1 + 8192);         // L*32 f32
  // arena: A0 [17M,33M) | B0 [33M,45M) | C0 [45M,49M) | D0 [49M,57M)
  char* A0 = wsb + 17 * MB1;
  ushort* src_bf = (ushort*)A0;              // steps 1-3 (4MiB)
  ushort* pprt   = (ushort*)A0;              // step 10-10.5 (8MiB)
  ushort* ff_bf  = (ushort*)A0;              // steps 12-13 (16MiB)
  float*  x0     = (float*)(A0 + 8 * MB1);   // steps 6-11 (8MiB)
  char* B0 = A0 + 16 * MB1;
  ushort* Qb = (ushort*)B0;                  // steps 3-4
  ushort* Kb = (ushort*)(B0 + 4 * MB1);
  ushort* Vb = (ushort*)(B0 + 8 * MB1);
  ushort* glu_bf = (ushort*)B0;              // steps 8-9 (4MiB)
  ushort* xln_bf = (ushort*)(B0 + 8 * MB1);  // steps 6-8 (4MiB)
  ushort* cat_bf = (ushort*)(B0 + 4 * MB1);  // steps 9-11 (8MiB)
  float*  zprt   = (float*)B0;               // step 13-14 (16MiB)
  char* C0 = B0 + 12 * MB1;
  ushort* ctx_bf = (ushort*)C0;              // steps 4-5
  ushort* x0T    = (ushort*)C0;              // steps 7-10
  ushort* y_bf   = (ushort*)C0;              // steps 11-12
  char* D0 = C0 + 4 * MB1;
  float* attnout = (float*)D0;               // steps 5-6
  float* y       = (float*)D0;               // steps 11-14 (8MiB)

  dim3 blk(256);

  // 1. convert weights + src to bf16
  CvtArgs ca;
  for (int i = 0; i < 11; ++i) ca.pm[i] = 0;
  ca.s[0] = Wq;     ca.d[0] = wqkv;              ca.n[0] = 512 * 512;
  ca.s[1] = Wk;     ca.d[1] = wqkv + 512 * 512;  ca.n[1] = 512 * 512;
  ca.s[2] = Wv;     ca.d[2] = wqkv + 1024 * 512; ca.n[2] = 512 * 512;
  ca.s[3] = Wo;     ca.d[3] = wo_w;              ca.n[3] = 512 * 512;
  ca.s[4] = pw1_w;  ca.d[4] = pw1w;              ca.n[4] = 1024 * 512; ca.pm[4] = 1;
  ca.s[5] = pw2_w;  ca.d[5] = wcat;              ca.n[5] = 512 * 512;  ca.pm[5] = 3;
  ca.s[6] = proj_w; ca.d[6] = pjww;              ca.n[6] = 2048 * 2048;
  ca.s[7] = proj2_w;ca.d[7] = wcat;              ca.n[7] = 512 * 512;  ca.pm[7] = 2;
  ca.s[8] = W1;     ca.d[8] = w1w;               ca.n[8] = 2048 * 512;
  ca.s[9] = W2;     ca.d[9] = w2w;               ca.n[9] = 512 * 2048;
  ca.s[10]= src;    ca.d[10]= src_bf;            ca.n[10]= BL_ * D_;
  cvt_all_k<<<dim3(2048, 11), blk, 0, stream>>>(ca);
  misc_k<<<dim3(129), blk, 0, stream>>>(tab, bq, bk, bv, bqkv, proj2_b, pw2_b, bcat);

  // 3. fused QKV + bias + RoPE
  gemm_bf_k<64,128,1,0,0,0,0,0,0><<<dim3(12, 64), blk, 0, stream>>>(
      src_bf, wqkv, bqkv, nullptr, nullptr, nullptr,
      BL_, 1536, 512, 0, 0, 1536, tab, Qb, Kb, Vb);

  // 4. attention (r12 single-buffer form, padded K_lds)
  attn_mfma_k<<<dim3(512), dim3(512), 0, stream>>>(Qb, Kb, Vb, ctx_bf);

  // 5. Wo  ((64,64) tile — r13 best)
  gemm_bf_k<64,64,0,0,0,0,1,0,0><<<dim3(8, 64), blk, 0, stream>>>(
      ctx_bf, wo_w, bo, nullptr, attnout, nullptr,
      BL_, 512, 512, 0, 0, 512, nullptr, nullptr, nullptr, nullptr);

  // 6. x0 = src + LN(attnout); xln_bf = LN(x0)
  ln_res_ln_k<<<BL_, 64, 0, stream>>>(attnout, src, n1_g, n1_b, ln_g, ln_b,
                                      x0, xln_bf);

  // 7. transpose x0 -> x0T bf16
  transp_k<<<dim3(64, 16, 2), blk, 0, stream>>>(x0, x0T);

  // 8. pw1 + fused GLU -> glu_bf
  gemm_bf_k<64,128,2,0,0,0,0,1,0><<<dim3(8, 64), blk, 0, stream>>>(
      xln_bf, pw1w, pw1_b, nullptr, nullptr, glu_bf,
      BL_, 1024, 512, 0, 0, 512, nullptr, nullptr, nullptr, nullptr);

  // 9. conv + bn + hswish -> cat[:,512:1024]
  convbn_k<<<(B_ * L_ * (D_ / 4)) / 256, blk, 0, stream>>>(
      glu_bf, dw_w, dw_b, bn_g, bn_b, cat_bf + 512);

  // 10. proj split-K x2 ((64,64)) -> pprt, 10.5 combine
  gemm_bf_k<64,64,0,0,0,0,0,1,1><<<dim3(8, 32, 4), blk, 0, stream>>>(
      pjww, x0T, nullptr, nullptr, nullptr, pprt,
      2048, 512, 1024, (long)512 * 2048, (long)2048 * 512, 512,
      nullptr, nullptr, nullptr, nullptr);
  cmb_proj_k<<<dim3(2048), blk, 0, stream>>>(pprt, proj_b, cat_bf);

  // 11. fused (proj2 + pw2) cat-GEMM ((64,64))
  gemm_bf_k<64,64,0,0,0,1,1,1,0><<<dim3(8, 64), blk, 0, stream>>>(
      cat_bf, wcat, bcat, x0, y, y_bf,
      BL_, 512, 1024, 0, 0, 512, nullptr, nullptr, nullptr, nullptr);

  // 12. W1 + fast-gelu -> ff_bf
  gemm_bf_k<64,128,0,0,1,0,0,1,0><<<dim3(16, 64), blk, 0, stream>>>(
      y_bf, w1w, b1, nullptr, nullptr, ff_bf,
      BL_, 2048, 512, 0, 0, 2048, nullptr, nullptr, nullptr, nullptr);

  // 13. W2 split-K x2 ((64,64)) -> zprt f32
  gemm_bf_k<64,64,0,0,0,0,1,0,1><<<dim3(8, 64, 2), blk, 0, stream>>>(
      ff_bf, w2w, nullptr, nullptr, zprt, nullptr,
      BL_, 512, 1024, 0, (long)BL_ * 512, 512,
      nullptr, nullptr, nullptr, nullptr);

  // 14. final LN over zA+zB+b2+y
  ln2_k<<<BL_, 64, 0, stream>>>(zprt, zprt + (size_t)BL_ * 512, y, b2,
                                n2_g, n2_b, out);
}